// Round 8
// baseline (715.144 us; speedup 1.0000x reference)
//
#include <hip/hip_runtime.h>
#include <hip/hip_fp16.h>

// NLSPN deformable propagation, B=4, H=480, W=640, 18 steps.
// Round 8: LDS-tiled gathers. Each block owns a 64x20 tile; per step it
// stages tile+8-halo (80x36 f32 = 11.5 KB) into LDS coalesced, then all
// bilinear gathers hit LDS (descriptor rel is tile-relative). Rare samples
// outside the halo (|offset|>~7) use a sentinel -> global fallback via an
// absolute-index side array (exact for any offset). 18 plain launches; no
// co-residency assumptions. Weight folding identical to R5-R7 (absmax 8192).

#define HH 480
#define WW 640
#define BB 4
#define HWSZ (HH * WW)        // 307200
#define NPIX (BB * HWSZ)      // 1228800
#define PROP_T 18
#define SLACK 704             // slack floats each side of state buffers
#define NTHR 256
#define TW 64                 // tile width
#define TH 20                 // tile height
#define HALO 8
#define TCW (TW + 2 * HALO)   // 80 LDS row stride
#define TR  (TH + 2 * HALO)   // 36 LDS rows
#define SENT 0x7FFFu          // tile-rel sentinel -> global fallback

__device__ __forceinline__ float fast_tanh(float x) {
    x = fminf(fmaxf(x, -15.0f), 15.0f);
    float e = __expf(2.0f * x);
    return __fdividef(e - 1.0f, e + 1.0f);
}

__device__ __forceinline__ float affinities(const float* gb, float inv_scale,
                                            float t[8]) {
    float ssum = 1e-4f;
#pragma unroll
    for (int j = 0; j < 8; ++j) {
        float v = fast_tanh(gb[(16 + j) * HWSZ]) * inv_scale;
        t[j] = v; ssum += fabsf(v);
    }
    ssum = fmaxf(ssum, 1.0f);
    float rs = __fdividef(1.0f, ssum);
    float asum = 0.0f;
#pragma unroll
    for (int j = 0; j < 8; ++j) { t[j] *= rs; asum += t[j]; }
    return 1.0f - asum;
}

// Descriptor with tile-relative index (R4-R7 hardware-validated folding).
__device__ __forceinline__ void make_desc(int y, int x, int k,
                                          float dy, float dx, float ak,
                                          int tY0, int tX0, int bBase,
                                          unsigned& pkT, unsigned short& akh,
                                          int& gidx) {
    float py = (float)(y + k / 3 - 1) + dy;
    float px = (float)(x + k % 3 - 1) + dx;
    float y0f = floorf(py), x0f = floorf(px);
    float wy = py - y0f, wx = px - x0f;
    int y0 = (int)y0f, x0 = (int)x0f;
    if (y0 == -1)                 { ak *= wy;        wy = 1.0f; }
    else if (y0 == HH - 1)        { ak *= 1.0f - wy; wy = 0.0f; }
    else if (y0 < -1 || y0 >= HH) { ak = 0.0f; }
    if (x0 == -1)                 { ak *= wx;        wx = 1.0f; }
    else if (x0 == WW - 1)        { ak *= 1.0f - wx; wx = 0.0f; }
    else if (x0 < -1 || x0 >= WW) { ak = 0.0f; }

    unsigned lrel;
    if (ak == 0.0f) {
        wy = 0.0f; wx = 0.0f;
        lrel = (unsigned)((y - tY0 + HALO) * TCW + (x - tX0 + HALO));
        gidx = bBase + y * WW + x;
    } else {
        int yc = min(max(y0, -1), HH - 1);
        int xc = min(max(x0, -1), WW - 1);
        gidx = bBase + yc * WW + xc;           // absolute; slack-safe
        int lyc = yc - tY0 + HALO;
        int lxc = xc - tX0 + HALO;
        lrel = (lyc >= 0 && lyc <= TR - 2 && lxc >= 0 && lxc <= TCW - 2)
             ? (unsigned)(lyc * TCW + lxc) : SENT;
    }
    unsigned uy = (unsigned)(int)(wy * 255.0f + 0.5f);
    unsigned ux = (unsigned)(int)(wx * 255.0f + 0.5f);
    pkT = (lrel << 16) | (uy << 8) | ux;
    akh = __half_as_ushort(__float2half(ak));
}

__device__ __forceinline__ float samp(const float* __restrict__ tile,
                                      const float* __restrict__ fin,
                                      const int* __restrict__ gidxArr,
                                      int pix, int n,
                                      unsigned pk, unsigned short akh,
                                      float acc) {
    unsigned lrel = pk >> 16;
    float wy = (float)((pk >> 8) & 0xffu) * (1.0f / 255.0f);
    float wx = (float)(pk & 0xffu) * (1.0f / 255.0f);
    float ak = __half2float(__ushort_as_half(akh));
    float r00, r01, r10, r11;
    if (__builtin_expect(lrel != SENT, 1)) {
        const float* p = tile + lrel;
        r00 = p[0]; r01 = p[1]; r10 = p[TCW]; r11 = p[TCW + 1];
    } else {
        const float* g = fin + gidxArr[(size_t)pix * 8 + n];
        r00 = g[0]; r01 = g[1]; r10 = g[WW]; r11 = g[WW + 1];
    }
    float bot = ak * wy;
    float top = ak - bot;
    float omwx = 1.0f - wx;
    acc = fmaf(top * omwx, r00, acc);
    acc = fmaf(top * wx,   r01, acc);
    acc = fmaf(bot * omwx, r10, acc);
    acc = fmaf(bot * wx,   r11, acc);
    return acc;
}

// ---------------- one-time descriptor build ----------------
__global__ __launch_bounds__(NTHR) void precompute_kernel(
    const float* __restrict__ feat_init,
    const float* __restrict__ guid,
    const float* __restrict__ confidence,
    const float* __restrict__ feat_fix,
    const float* __restrict__ aff_scale,
    float* __restrict__ g0,               // state init (interior base of bufA)
    unsigned* __restrict__ pkTArr,        // [NPIX][8] tile-rel packed
    unsigned short* __restrict__ akArr,   // [NPIX][8]
    uint2* __restrict__ cfArr,            // {aref16|conf16, bits(m*ff)}
    int* __restrict__ gidxArr) {          // [NPIX][8] absolute (fallback)
    const int pix = blockIdx.x * NTHR + threadIdx.x;
    const int b = pix / HWSZ;
    const int q = pix - b * HWSZ;
    const int y = q / WW;
    const int x = q - y * WW;
    const int bBase = b * HWSZ;
    const int tY0 = (y / TH) * TH;
    const int tX0 = (x / TW) * TW;
    const float* gb = guid + (size_t)b * 24 * HWSZ + q;

    float ff = feat_fix[pix];
    float m  = (ff > 0.0f) ? 1.0f : 0.0f;
    float km = 1.0f - m;
    float conf = km * confidence[pix] + m;
    float f0   = km * feat_init[pix] + m * ff;
    g0[pix] = f0 * conf;

    const float inv_scale = __fdividef(1.0f, aff_scale[0] + 1e-8f);
    float t[8];
    float aref = affinities(gb, inv_scale, t);
    uint2 cf;
    cf.x = ((unsigned)__half_as_ushort(__float2half(aref)) << 16)
         | (unsigned)__half_as_ushort(__float2half(conf));
    cf.y = __float_as_uint(m * ff);
    cfArr[pix] = cf;

    unsigned pk[8];
    unsigned short akh[8];
    int gi[8];
#pragma unroll
    for (int n = 0; n < 8; ++n) {
        const int k = (n < 4) ? n : (n + 1);
        float dy = gb[(2 * n) * HWSZ];
        float dx = gb[(2 * n + 1) * HWSZ];
        make_desc(y, x, k, dy, dx, t[n], tY0, tX0, bBase, pk[n], akh[n], gi[n]);
    }
    uint4* pd = reinterpret_cast<uint4*>(pkTArr) + 2 * (size_t)pix;
    pd[0] = make_uint4(pk[0], pk[1], pk[2], pk[3]);
    pd[1] = make_uint4(pk[4], pk[5], pk[6], pk[7]);
    uint4 kv;
    kv.x = (unsigned)akh[0] | ((unsigned)akh[1] << 16);
    kv.y = (unsigned)akh[2] | ((unsigned)akh[3] << 16);
    kv.z = (unsigned)akh[4] | ((unsigned)akh[5] << 16);
    kv.w = (unsigned)akh[6] | ((unsigned)akh[7] << 16);
    reinterpret_cast<uint4*>(akArr)[pix] = kv;
    int4* gd = reinterpret_cast<int4*>(gidxArr) + 2 * (size_t)pix;
    gd[0] = make_int4(gi[0], gi[1], gi[2], gi[3]);
    gd[1] = make_int4(gi[4], gi[5], gi[6], gi[7]);
}

// ---------------- per-step kernel: stage tile in LDS, gather from LDS ----------------
__global__ __launch_bounds__(NTHR) void step_tile_kernel(
    const float* __restrict__ fin,
    float* __restrict__ fout,
    const unsigned* __restrict__ pkTArr,
    const unsigned short* __restrict__ akArr,
    const uint2* __restrict__ cfArr,
    const int* __restrict__ gidxArr,
    int last)
{
    __shared__ float tile[TR * TCW];     // 80*36*4 = 11.52 KB
    const int tX0 = blockIdx.x * TW;
    const int tY0 = blockIdx.y * TH;
    const int b   = blockIdx.z;
    const int bBase = b * HWSZ;
    const int lx = threadIdx.x & 63;
    const int ry = threadIdx.x >> 6;

    // stage tile + halo (coalesced along rows); out-of-image cells = 0
    const int y0g = tY0 - HALO;
    const int x0g = tX0 - HALO;
    for (int j = threadIdx.x; j < TR * TCW; j += NTHR) {
        int r = j / TCW, c = j - r * TCW;
        int gy = y0g + r, gx = x0g + c;
        float v = 0.0f;
        if (gy >= 0 && gy < HH && gx >= 0 && gx < WW)
            v = fin[bBase + gy * WW + gx];
        tile[j] = v;
    }
    __syncthreads();

#pragma unroll
    for (int i = 0; i < 5; ++i) {
        const int yy = ry + 4 * i;                 // tile row 0..19
        const int pix = bBase + (tY0 + yy) * WW + tX0 + lx;
        const uint4* pd = reinterpret_cast<const uint4*>(pkTArr) + 2 * (size_t)pix;
        uint4 A = pd[0], B = pd[1];
        uint4 K = reinterpret_cast<const uint4*>(akArr)[pix];
        uint2 c2 = cfArr[pix];
        float aref = __half2float(__ushort_as_half((unsigned short)(c2.x >> 16)));
        float conf = __half2float(__ushort_as_half((unsigned short)(c2.x & 0xffffu)));
        float acc = aref * tile[(yy + HALO) * TCW + lx + HALO];
        acc = samp(tile, fin, gidxArr, pix, 0, A.x, (unsigned short)(K.x & 0xffffu), acc);
        acc = samp(tile, fin, gidxArr, pix, 1, A.y, (unsigned short)(K.x >> 16),     acc);
        acc = samp(tile, fin, gidxArr, pix, 2, A.z, (unsigned short)(K.y & 0xffffu), acc);
        acc = samp(tile, fin, gidxArr, pix, 3, A.w, (unsigned short)(K.y >> 16),     acc);
        acc = samp(tile, fin, gidxArr, pix, 4, B.x, (unsigned short)(K.z & 0xffffu), acc);
        acc = samp(tile, fin, gidxArr, pix, 5, B.y, (unsigned short)(K.z >> 16),     acc);
        acc = samp(tile, fin, gidxArr, pix, 6, B.z, (unsigned short)(K.w & 0xffffu), acc);
        acc = samp(tile, fin, gidxArr, pix, 7, B.w, (unsigned short)(K.w >> 16),     acc);
        float mff = __uint_as_float(c2.y);
        float km = (mff > 0.0f) ? 0.0f : 1.0f;
        float fnew = fmaf(km, acc, mff);            // f' = km*prop + m*ff
        fout[pix] = last ? fnew : conf * fnew;      // g' = f'*conf
    }
}

extern "C" void kernel_launch(void* const* d_in, const int* in_sizes, int n_in,
                              void* d_out, int out_size, void* d_ws, size_t ws_size,
                              hipStream_t stream) {
    const float* feat_init  = (const float*)d_in[0];
    const float* guidance   = (const float*)d_in[1];
    const float* confidence = (const float*)d_in[2];
    const float* feat_fix   = (const float*)d_in[3];
    const float* aff_scale  = (const float*)d_in[4];

    // ws layout: bufA | bufB | pkT | ak | cf | gidx   (~118 MB of ~450 MiB)
    const size_t bufFloats = (size_t)NPIX + 2 * SLACK;
    float* bufA = (float*)d_ws;
    float* bufB = bufA + bufFloats;
    unsigned* pkTArr = (unsigned*)(bufB + bufFloats);
    unsigned short* akArr = (unsigned short*)(pkTArr + 8 * (size_t)NPIX);
    uint2* cfArr = (uint2*)(akArr + 8 * (size_t)NPIX);
    int* gidxArr = (int*)(cfArr + NPIX);
    float* fA = bufA + SLACK;
    float* fB = bufB + SLACK;
    float* outp = (float*)d_out;

    // zero slack strips (fallback gathers may touch them; weight always 0)
    hipMemsetAsync(bufA, 0, SLACK * sizeof(float), stream);
    hipMemsetAsync(bufA + SLACK + NPIX, 0, SLACK * sizeof(float), stream);
    hipMemsetAsync(bufB, 0, SLACK * sizeof(float), stream);
    hipMemsetAsync(bufB + SLACK + NPIX, 0, SLACK * sizeof(float), stream);

    precompute_kernel<<<NPIX / NTHR, NTHR, 0, stream>>>(
        feat_init, guidance, confidence, feat_fix, aff_scale,
        fA, pkTArr, akArr, cfArr, gidxArr);

    dim3 grd(WW / TW, HH / TH, BB);   // 10 x 24 x 4 = 960 blocks
    for (int t = 0; t < PROP_T; ++t) {
        const float* fin = (t & 1) ? fB : fA;
        float* fout = (t == PROP_T - 1) ? outp : ((t & 1) ? fA : fB);
        step_tile_kernel<<<grd, NTHR, 0, stream>>>(
            fin, fout, pkTArr, akArr, cfArr, gidxArr, (t == PROP_T - 1) ? 1 : 0);
    }
}